// Round 8
// baseline (530.973 us; speedup 1.0000x reference)
//
#include <hip/hip_runtime.h>

// DIAGNOSTIC ROUND. Same algorithm as R7, but K2 writes its computed 32 KB
// slab 5x: passes 0..3 into d_ws (scratch, harness re-poisons it anyway),
// final pass into d_out (so output is exactly as before; absmax 0).
// Purpose: the harness's top-5 dispatch table is saturated by ~163 us 1 GB
// fillBuffer restores, hiding our ~<80 us kernels. The 5x store loop makes
// K2 ~170-200 us => its own dur/FETCH/WRITE/hbm_gbps surface, giving a
// direct measurement of OUR store stream's sustained BW vs fillBuffer's
// 6.5 TB/s. Store values are computed once into registers before the loop,
// so the repeated passes are pure register-fed global stores.

#define BATCH   32
#define DIM     384
#define T_TEXT  512
#define T_MEL   4096
#define WIN     48
#define ROWS    2     // d-rows per K2 block (32 KB contiguous output slab)
#define NTOT    ((size_t)BATCH * DIM * T_MEL)   // elements per full output image

typedef float nfloat4 __attribute__((ext_vector_type(4)));

__global__ __launch_bounds__(256) void find_idx_kernel(
    const float* __restrict__ path,    // [B, T_TEXT, T_MEL]
    int*   __restrict__ idx_ws,        // [B, T_MEL]
    float* __restrict__ scale_ws)      // [B, T_MEL]
{
    const int b = blockIdx.y;
    const int m = blockIdx.x * 256 + threadIdx.x;
    const float* pcol = path + (size_t)b * T_TEXT * T_MEL + m;

    int start = ((m & ~63) >> 3) - 20;
    if (start < 0) start = 0;
    if (start > T_TEXT - WIN) start = T_TEXT - WIN;

    int   idx   = 0;
    float scale = 0.0f;
    bool  found = false;

    float v[WIN];
    #pragma unroll
    for (int j = 0; j < WIN; ++j)
        v[j] = pcol[(size_t)(start + j) * T_MEL];
    #pragma unroll
    for (int j = 0; j < WIN; ++j)
        if (v[j] != 0.0f) { idx = start + j; scale = v[j]; found = true; }

    if (!__all(found)) {                // guaranteed-correct fallback (rare)
        for (int n = 0; n < T_TEXT; n += 16) {
            float u[16];
            #pragma unroll
            for (int j = 0; j < 16; ++j) u[j] = pcol[(size_t)(n + j) * T_MEL];
            #pragma unroll
            for (int j = 0; j < 16; ++j)
                if (!found && u[j] != 0.0f) { idx = n + j; scale = u[j]; found = true; }
            if (__all(found)) break;
        }
    }
    idx_ws[b * T_MEL + m]   = idx;
    scale_ws[b * T_MEL + m] = scale;
}

__global__ __launch_bounds__(256) void gather_kernel(
    const float* __restrict__ x,        // [B, D, T_TEXT]
    const int*   __restrict__ idx_ws,   // [B, T_MEL]
    const float* __restrict__ scale_ws, // [B, T_MEL]
    float* __restrict__ scratch,        // >= nrep * NTOT floats (diag targets)
    int nrep,                           // extra write passes into scratch
    float* __restrict__ out)            // [B, D, T_MEL]
{
    const int dg = blockIdx.x;          // d-group (2 rows)
    const int b  = blockIdx.y;
    const int t  = threadIdx.x;

    __shared__ float xs[ROWS * T_TEXT];

    // ---- all vmem loads up front ----------------------------------------
    const float* xr = x + ((size_t)b * DIM + dg * ROWS) * T_TEXT;
    const nfloat4 xstage = *(const nfloat4*)(xr + t * 4);

    const int*   ip = idx_ws   + b * T_MEL;
    const float* sp = scale_ws + b * T_MEL;
    int4   i4[4];
    float4 s4[4];
    #pragma unroll
    for (int s = 0; s < 4; ++s) {
        const int m4 = s * 1024 + t * 4;
        i4[s] = *(const int4*)  (ip + m4);
        s4[s] = *(const float4*)(sp + m4);
    }
    *(nfloat4*)(xs + t * 4) = xstage;
    __syncthreads();

    // ---- compute the block's slab values ONCE into registers -------------
    nfloat4 o[ROWS][4];
    #pragma unroll
    for (int r = 0; r < ROWS; ++r) {
        const float* xsr = xs + r * T_TEXT;
        #pragma unroll
        for (int s = 0; s < 4; ++s) {
            o[r][s].x = xsr[i4[s].x] * s4[s].x;
            o[r][s].y = xsr[i4[s].y] * s4[s].y;
            o[r][s].z = xsr[i4[s].z] * s4[s].z;
            o[r][s].w = xsr[i4[s].w] * s4[s].w;
        }
    }

    const size_t slab = ((size_t)b * DIM + dg * ROWS) * T_MEL;

    // ---- diagnostic passes: pure register-fed store stream into scratch --
    for (int rep = 0; rep < nrep; ++rep) {
        float* tb = scratch + (size_t)rep * NTOT + slab;
        #pragma unroll
        for (int r = 0; r < ROWS; ++r)
            #pragma unroll
            for (int s = 0; s < 4; ++s)
                *(nfloat4*)(tb + (size_t)r * T_MEL + s * 1024 + t * 4) = o[r][s];
    }

    // ---- final (real) pass into out --------------------------------------
    float* ob = out + slab;
    #pragma unroll
    for (int r = 0; r < ROWS; ++r)
        #pragma unroll
        for (int s = 0; s < 4; ++s)
            *(nfloat4*)(ob + (size_t)r * T_MEL + s * 1024 + t * 4) = o[r][s];
}

extern "C" void kernel_launch(void* const* d_in, const int* in_sizes, int n_in,
                              void* d_out, int out_size, void* d_ws, size_t ws_size,
                              hipStream_t stream) {
    (void)in_sizes; (void)n_in; (void)out_size;
    const float* x    = (const float*)d_in[0];   // [32, 384, 512]
    const float* path = (const float*)d_in[1];   // [32, 512, 4096]
    float*       out  = (float*)d_out;           // [32, 384, 4096]

    int*   idx_ws   = (int*)d_ws;                          // 512 KB
    float* scale_ws = (float*)((char*)d_ws + (size_t)BATCH * T_MEL * sizeof(int));
    // diag scratch after the 1 MB idx/scale area, 256 B aligned
    float* scratch  = (float*)((char*)d_ws + 2 * (size_t)BATCH * T_MEL * sizeof(int));

    const size_t region = NTOT * sizeof(float);            // 201 MB per pass
    const size_t avail  = ws_size > (2u * BATCH * T_MEL * sizeof(int))
                        ? ws_size - 2 * (size_t)BATCH * T_MEL * sizeof(int) : 0;
    int nrep = (int)(avail / region);
    if (nrep > 4) nrep = 4;                                // target ~175 us dispatch

    dim3 g1(T_MEL / 256, BATCH);
    find_idx_kernel<<<g1, dim3(256), 0, stream>>>(path, idx_ws, scale_ws);

    dim3 g2(DIM / ROWS, BATCH);           // 6144 blocks
    gather_kernel<<<g2, dim3(256), 0, stream>>>(x, idx_ws, scale_ws,
                                                scratch, nrep, out);
}

// Round 9
// 383.419 us; speedup vs baseline: 1.3848x; 1.3848x over previous
//
#include <hip/hip_runtime.h>

// LengthRegulator: out[b,d,m] = x[b, d, idx[b,m]] * path[b, idx[b,m], m]
// (path one-hot along text axis, idx sorted along m).
//
// R9: single fused kernel, BARRIER-FREE, NO LDS. 512 blocks x 256 threads;
// each wave is fully autonomous over 64 columns:
//   Phase 1 (per wave): idx[m] ~ m/8 (m-th order statistic of 4096 uniforms
//     over [0,512), sigma ~4). One group of 48 outstanding loads covers
//     [m/8-20, m/8+28) => single vmcnt round-trip. Full-rescan fallback
//     keeps correctness for arbitrary input.
//   Redistribute (per wave): lane l serves columns 4*(l&15)..+3 at d-offset
//     (l>>4); idx/scale pulled from owner lanes via __shfl (no LDS, no
//     barrier).
//   Phase 2 (per wave): 96 sweeps of 4 d-rows: 4 x-gathers (L1/L3-hot,
//     clustered) + one 16 B store (wave: 4 x 256 B segments / instr).
// Why: R8 diag measured our store machinery at 5.1 TB/s (occupancy/vmcnt/nt
// theories all disproven); the 74-81 us plateau = SERIAL (23 us DRAM-pattern-
// limited band read) + (47 us store stream), enforced by block-level lockstep
// at barriers. Removing all intra-block sync lets waves enter the store phase
// as their band reads complete => the two DRAM phases overlap.

#define BATCH   32
#define DIM     384
#define T_TEXT  512
#define T_MEL   4096
#define WIN     48

typedef float nfloat4 __attribute__((ext_vector_type(4)));

__global__ __launch_bounds__(256) void length_regulator_fused(
    const float* __restrict__ x,      // [B, D, T_TEXT]
    const float* __restrict__ path,   // [B, T_TEXT, T_MEL]
    float* __restrict__ out)          // [B, D, T_MEL]
{
    const int mt = blockIdx.x;
    const int b  = blockIdx.y;
    const int t  = threadIdx.x;
    const int m  = mt * 256 + t;       // this thread's column (phase 1 owner)
    const int l  = t & 63;             // lane

    // ---- Phase 1: single-round-trip window scan --------------------------
    const float* pcol = path + (size_t)b * T_TEXT * T_MEL + m;
    int start = ((m & ~63) >> 3) - 20; // wave-uniform
    if (start < 0) start = 0;
    if (start > T_TEXT - WIN) start = T_TEXT - WIN;

    int   idx   = 0;
    float scale = 0.0f;
    bool  found = false;

    float v[WIN];
    #pragma unroll
    for (int j = 0; j < WIN; ++j)      // 48 loads in flight, ONE drain
        v[j] = pcol[(size_t)(start + j) * T_MEL];
    #pragma unroll
    for (int j = 0; j < WIN; ++j)
        if (v[j] != 0.0f) { idx = start + j; scale = v[j]; found = true; }

    if (!__all(found)) {               // guaranteed-correct fallback (rare)
        for (int n = 0; n < T_TEXT; n += 16) {
            float u[16];
            #pragma unroll
            for (int j = 0; j < 16; ++j) u[j] = pcol[(size_t)(n + j) * T_MEL];
            #pragma unroll
            for (int j = 0; j < 16; ++j)
                if (!found && u[j] != 0.0f) { idx = n + j; scale = u[j]; found = true; }
            if (__all(found)) break;
        }
    }

    // ---- Redistribute within the wave (no LDS, no barrier) ---------------
    // Lane l handles columns wavebase + 4*(l&15) + j, at d-rows (l>>4) + 4k.
    const int cl = (l & 15) * 4;       // lane's first column within the wave
    const int dl = l >> 4;             // lane's d-row offset (0..3)
    const int i0 = __shfl(idx,   cl + 0), i1 = __shfl(idx,   cl + 1),
              i2 = __shfl(idx,   cl + 2), i3 = __shfl(idx,   cl + 3);
    const float s0 = __shfl(scale, cl + 0), s1 = __shfl(scale, cl + 1),
                s2 = __shfl(scale, cl + 2), s3 = __shfl(scale, cl + 3);

    // ---- Phase 2: stream stores, per-wave, immediately -------------------
    const float* xb = x + (size_t)b * DIM * T_TEXT;
    float* ob = out + (size_t)b * DIM * T_MEL      // batch base
              + (size_t)(m & ~63) + cl;            // wave's columns + lane cols

    #pragma unroll 4
    for (int d = dl; d < DIM; d += 4) {
        const float* xr = xb + (size_t)d * T_TEXT;
        nfloat4 o;
        o.x = xr[i0] * s0;             // clustered gathers: L1/L3-hot x rows
        o.y = xr[i1] * s1;
        o.z = xr[i2] * s2;
        o.w = xr[i3] * s3;
        *(nfloat4*)(ob + (size_t)d * T_MEL) = o;   // wave: 4 x 256 B segments
    }
}

extern "C" void kernel_launch(void* const* d_in, const int* in_sizes, int n_in,
                              void* d_out, int out_size, void* d_ws, size_t ws_size,
                              hipStream_t stream) {
    (void)in_sizes; (void)n_in; (void)d_ws; (void)ws_size; (void)out_size;
    const float* x    = (const float*)d_in[0];   // [32, 384, 512]
    const float* path = (const float*)d_in[1];   // [32, 512, 4096]
    float*       out  = (float*)d_out;           // [32, 384, 4096]

    dim3 grid(T_MEL / 256, BATCH);               // (16, 32) = 512 blocks
    length_regulator_fused<<<grid, dim3(256), 0, stream>>>(x, path, out);
}